// Round 4
// baseline (963.401 us; speedup 1.0000x reference)
//
#include <hip/hip_runtime.h>
#include <stdint.h>

// ---------- helpers ----------
typedef __attribute__((ext_vector_type(8))) short short8;
typedef __attribute__((ext_vector_type(4))) short short4v;
typedef __attribute__((ext_vector_type(4))) float float4v;

__device__ inline float b2f(unsigned short u) {
  union { unsigned int i; float f; } v; v.i = ((unsigned int)u) << 16; return v.f;
}
__device__ inline unsigned short f2b(float f) {
  union { float f; unsigned int i; } v; v.f = f;
  unsigned int i = v.i;
  i += 0x7fffu + ((i >> 16) & 1u);   // round-to-nearest-even
  return (unsigned short)(i >> 16);
}

// ---------- transpose fp32 -> bf16, zero-padded output (pad pre-zeroed by memset) ----------
__global__ void transpose_pad(const float* __restrict__ in, short* __restrict__ out,
                              int R, int C, int outStride, int total) {
  int idx = blockIdx.x * blockDim.x + threadIdx.x;
  if (idx >= total) return;
  int r = idx / C, c = idx - r * C;
  out[(size_t)c * outStride + r] = (short)f2b(in[idx]);
}

// ---------- CSR build: count, scan, fill ----------
__global__ void count_deg(const int* __restrict__ dst, int* __restrict__ deg, int E) {
  int e = blockIdx.x * blockDim.x + threadIdx.x;
  if (e < E) atomicAdd(&deg[dst[e]], 1);
}

__global__ void scan1(const int* __restrict__ deg, int* __restrict__ offp,
                      int* __restrict__ bsum, int n) {
  __shared__ int sh[256];
  const int t = threadIdx.x;
  const int base = blockIdx.x * 1024 + t * 4;
  int v[4], s = 0;
#pragma unroll
  for (int j = 0; j < 4; ++j) { int i = base + j; v[j] = (i < n) ? deg[i] : 0; s += v[j]; }
  sh[t] = s;
  __syncthreads();
  for (int d = 1; d < 256; d <<= 1) {
    int x = (t >= d) ? sh[t - d] : 0;
    __syncthreads();
    sh[t] += x;
    __syncthreads();
  }
  int excl = (t > 0) ? sh[t - 1] : 0;
  if (t == 255) bsum[blockIdx.x] = sh[255];
#pragma unroll
  for (int j = 0; j < 4; ++j) { int i = base + j; if (i < n) offp[i] = excl; excl += v[j]; }
}

__global__ void scan2(int* __restrict__ bsum, int nb) {
  __shared__ int sh[256];
  const int t = threadIdx.x;
  sh[t] = (t < nb) ? bsum[t] : 0;
  __syncthreads();
  for (int d = 1; d < 256; d <<= 1) {
    int x = (t >= d) ? sh[t - d] : 0;
    __syncthreads();
    sh[t] += x;
    __syncthreads();
  }
  if (t < nb) bsum[t] = (t > 0) ? sh[t - 1] : 0;
}

__global__ void fill_csr(const int* __restrict__ dst, const int* __restrict__ offp,
                         const int* __restrict__ bsum, int* __restrict__ tmp,
                         int* __restrict__ eb, int E) {
  int e = blockIdx.x * blockDim.x + threadIdx.x;
  if (e >= E) return;
  int dn = dst[e];
  int pos = offp[dn] + bsum[dn >> 10] + atomicAdd(&tmp[dn], 1);
  eb[pos] = e;
}

// ---------- gather: aggb[node] = sum_e (nf[src]+w0[ef0]+w1[ef1]) + deg*(b0+b1), bf16 out ----------
// one thread per (node, 16-col chunk): meta arrays read once per 16 cols
__global__ void gather_agg(const float* __restrict__ nf,
                           const int* __restrict__ src, const int* __restrict__ ef0,
                           const int* __restrict__ ef1,
                           const float* __restrict__ w0, const float* __restrict__ b0f,
                           const float* __restrict__ w1, const float* __restrict__ b1f,
                           const int* __restrict__ deg, const int* __restrict__ offp,
                           const int* __restrict__ bsum, const int* __restrict__ eb,
                           unsigned short* __restrict__ aggb,
                           int D, int ldab, int chunks, int total) {
  int idx = blockIdx.x * blockDim.x + threadIdx.x;
  if (idx >= total) return;
  int node = idx / chunks;
  int c16 = idx - node * chunks;
  int d0 = c16 * 16;
  unsigned short* op = &aggb[(size_t)node * ldab + d0];
  const short8 z8s = {0, 0, 0, 0, 0, 0, 0, 0};
  if (d0 >= D) {  // all-pad chunk
    *(short8*)op = z8s; *(short8*)(op + 8) = z8s;
    return;
  }
  int nv = (D - d0) >> 2; if (nv > 4) nv = 4;   // valid float4s in this chunk
  int dg = deg[node];
  int o = offp[node] + bsum[node >> 10];
  float4v acc[4];
#pragma unroll
  for (int jj = 0; jj < 4; ++jj) acc[jj] = (float4v){0.f, 0.f, 0.f, 0.f};
  for (int j = 0; j < dg; ++j) {
    int e = eb[o + j];
    int s = src[e], f0 = ef0[e], f1 = ef1[e];
    const float* nr = &nf[(size_t)s * D + d0];
    const float* r0 = &w0[(size_t)f0 * D + d0];
    const float* r1 = &w1[(size_t)f1 * D + d0];
#pragma unroll
    for (int jj = 0; jj < 4; ++jj)
      if (jj < nv)
        acc[jj] += *(const float4v*)(nr + 4 * jj) + *(const float4v*)(r0 + 4 * jj) +
                   *(const float4v*)(r1 + 4 * jj);
  }
  float fdg = (float)dg;
#pragma unroll
  for (int jj = 0; jj < 4; ++jj)
    if (jj < nv)
      acc[jj] += fdg * (*(const float4v*)(b0f + d0 + 4 * jj) + *(const float4v*)(b1f + d0 + 4 * jj));
  unsigned short r[16];
#pragma unroll
  for (int k = 0; k < 16; ++k) r[k] = 0;
#pragma unroll
  for (int jj = 0; jj < 4; ++jj)
    if (jj < nv) {
      r[jj * 4 + 0] = f2b(acc[jj][0]); r[jj * 4 + 1] = f2b(acc[jj][1]);
      r[jj * 4 + 2] = f2b(acc[jj][2]); r[jj * 4 + 3] = f2b(acc[jj][3]);
    }
  *(short8*)op = *(short8*)&r[0];
  *(short8*)(op + 8) = *(short8*)&r[8];
}

// ---------- A-resident MFMA GEMM ----------
// Block stages its full-K A-strip (BM x KP bf16, row stride KP) into LDS once,
// hoists per-wave A-fragments for ALL k-steps into registers, then loops n-tiles
// of 64 cols with a barrier-free, fully-unrolled MFMA loop fed by double-buffered
// global B loads (B = weights, L2-resident). KST = KP/32 k-steps, NT n-tiles.
// Wave layout: 2(m) x 2(n); each wave owns MF*16 rows x 32 cols per tile.
template<int BM, int KP, int SA, int KST, int NT, int MF, bool RELU, bool STATS, bool CF32>
__global__ __launch_bounds__(256)
void gemm_areg(const short* __restrict__ A,
               const short* __restrict__ BT,
               const float* __restrict__ bias,
               void* __restrict__ Cv, int ldc,
               int M, int Nn,
               float* __restrict__ colsum, float* __restrict__ colsumsq) {
  __shared__ __align__(16) short Al[BM * SA];
  const int t = threadIdx.x;
  const int m0 = blockIdx.x * BM;
  const int wave = t >> 6, lane = t & 63, quad = lane >> 4, lr = lane & 15;
  const int wm = (wave >> 1) * (MF * 16), wn = (wave & 1) * 32;

  // ---- stage A strip (once) ----
  constexpr int CPR = KP / 8;           // 16B chunks per row
  constexpr int TOT = BM * CPR;
  const short8 z8 = {0, 0, 0, 0, 0, 0, 0, 0};
#pragma unroll
  for (int i = 0; i < (TOT + 255) / 256; ++i) {
    int idx = t + i * 256;
    if ((TOT & 255) && idx >= TOT) break;
    int row = idx / CPR, ch = idx - row * CPR;
    int gm = m0 + row;
    short8 v = z8;
    if (gm < M) v = *(const short8*)&A[(size_t)gm * KP + ch * 8];
    *(short8*)&Al[row * SA + ch * 8] = v;
  }
  __syncthreads();

  // ---- hoist this wave's A-fragments for all k-steps into registers ----
  short8 af[MF][KST];
#pragma unroll
  for (int mi = 0; mi < MF; ++mi)
#pragma unroll
    for (int kk = 0; kk < KST; ++kk)
      af[mi][kk] = *(short8*)&Al[(wm + mi * 16 + lr) * SA + kk * 32 + quad * 8];

  // ---- n-tile loop: barrier-free MFMA with double-buffered B ----
  for (int nt = 0; nt < NT; ++nt) {
    const short* Bb = &BT[(size_t)(nt * 64 + wn + lr) * KP + quad * 8];
    short8 b0 = *(const short8*)Bb;
    short8 b1 = *(const short8*)(Bb + (size_t)16 * KP);
    float4v acc[MF][2];
#pragma unroll
    for (int mi = 0; mi < MF; ++mi) {
      acc[mi][0] = (float4v){0.f, 0.f, 0.f, 0.f};
      acc[mi][1] = (float4v){0.f, 0.f, 0.f, 0.f};
    }
#pragma unroll
    for (int kk = 0; kk < KST; ++kk) {
      short8 n0 = z8, n1 = z8;
      if (kk + 1 < KST) {
        n0 = *(const short8*)(Bb + (kk + 1) * 32);
        n1 = *(const short8*)(Bb + (size_t)16 * KP + (kk + 1) * 32);
      }
#pragma unroll
      for (int mi = 0; mi < MF; ++mi) {
        acc[mi][0] = __builtin_amdgcn_mfma_f32_16x16x32_bf16(af[mi][kk], b0, acc[mi][0], 0, 0, 0);
        acc[mi][1] = __builtin_amdgcn_mfma_f32_16x16x32_bf16(af[mi][kk], b1, acc[mi][1], 0, 0, 0);
      }
      b0 = n0; b1 = n1;
    }
    // ---- epilogue for this n-tile ----
#pragma unroll
    for (int ni = 0; ni < 2; ++ni) {
      int gn = nt * 64 + wn + ni * 16 + lr;
      bool ncol = (gn < Nn);
      float bv = ncol ? bias[gn] : 0.f;
      float s = 0.f, q = 0.f;
#pragma unroll
      for (int mi = 0; mi < MF; ++mi) {
        int gmb = m0 + wm + mi * 16 + quad * 4;
#pragma unroll
        for (int r = 0; r < 4; ++r) {
          int gm = gmb + r;
          float v = acc[mi][ni][r] + bv;
          if (RELU) v = fmaxf(v, 0.f);
          if (gm < M && ncol) {
            if constexpr (CF32) ((float*)Cv)[(size_t)gm * ldc + gn] = v;
            else ((unsigned short*)Cv)[(size_t)gm * ldc + gn] = f2b(v);
            if (STATS) { s += v; q += v * v; }
          }
        }
      }
      if constexpr (STATS) {
        s += __shfl_xor(s, 16); q += __shfl_xor(q, 16);
        s += __shfl_xor(s, 32); q += __shfl_xor(q, 32);
        if (quad == 0 && ncol) {
          unsafeAtomicAdd(&colsum[gn], s);
          unsafeAtomicAdd(&colsumsq[gn], q);
        }
      }
    }
  }
}

// ---------- BatchNorm finalize: per-column scale/shift ----------
__global__ void bn_finalize(const float* __restrict__ colsum, const float* __restrict__ colsumsq,
                            const float* __restrict__ gamma, const float* __restrict__ beta,
                            float* __restrict__ scale, float* __restrict__ shift,
                            int D, float invN) {
  int d = blockIdx.x * blockDim.x + threadIdx.x;
  if (d >= D) return;
  float mean = colsum[d] * invN;
  float var = fmaxf(colsumsq[d] * invN - mean * mean, 0.f);
  float sc = rsqrtf(var + 1e-5f) * gamma[d];
  scale[d] = sc;
  shift[d] = beta[d] - mean * sc;
}

// ---------- BatchNorm apply (in place on d_out, fp32, float4) ----------
__global__ void bn_apply(float* __restrict__ out, const float* __restrict__ scale,
                         const float* __restrict__ shift, int total4, int q4) {
  int idx = blockIdx.x * blockDim.x + threadIdx.x;
  if (idx >= total4) return;
  int row = idx / q4;
  int col = (idx - row * q4) * 4;
  float4v v = *(float4v*)&out[(size_t)row * (q4 * 4) + col];
  float4v sc = *(const float4v*)&scale[col];
  float4v sh = *(const float4v*)&shift[col];
  v = v * sc + sh;
  *(float4v*)&out[(size_t)row * (q4 * 4) + col] = v;
}

// ---------- launch ----------
extern "C" void kernel_launch(void* const* d_in, const int* in_sizes, int n_in,
                              void* d_out, int out_size, void* d_ws, size_t ws_size,
                              hipStream_t stream) {
  const float* nf  = (const float*)d_in[0];
  const int*   src = (const int*)d_in[1];
  const int*   dst = (const int*)d_in[2];
  const int*   ef0 = (const int*)d_in[3];
  const int*   ef1 = (const int*)d_in[4];
  const float* ew0 = (const float*)d_in[5];
  const float* eb0 = (const float*)d_in[6];
  const float* ew1 = (const float*)d_in[7];
  const float* eb1 = (const float*)d_in[8];
  const float* w1  = (const float*)d_in[9];
  const float* b1  = (const float*)d_in[10];
  const float* w2  = (const float*)d_in[11];
  const float* b2  = (const float*)d_in[12];
  const float* gam = (const float*)d_in[13];
  const float* bet = (const float*)d_in[14];

  const int D = in_sizes[13];        // 300
  const int N = in_sizes[0] / D;     // 100000
  const int E = in_sizes[1];         // 200000
  const int H = in_sizes[10];        // 600
  constexpr int KP1 = 320, NP1 = 640, KP2 = 608, NP2 = 320;
  const int nb = (N + 1023) / 1024;

  char* ws = (char*)d_ws;
  size_t off = 0;
  // ---- zeroed region ----
  float* colsum   = (float*)(ws + off); off += 4096;
  float* colsumsq = (float*)(ws + off); off += 4096;
  short* wT1      = (short*)(ws + off); off += (size_t)NP1 * KP1 * 2;
  short* wT2      = (short*)(ws + off); off += (size_t)NP2 * KP2 * 2;
  int*   deg      = (int*)(ws + off);   off += (size_t)N * 4;
  int*   tmp      = (int*)(ws + off);   off += (size_t)N * 4;
  size_t zero_bytes = off;
  // ---- uninitialized region ----
  float* scale    = (float*)(ws + off); off += 4096;
  float* shiftv   = (float*)(ws + off); off += 4096;
  int*   offp     = (int*)(ws + off);   off += (size_t)N * 4;
  int*   bsum     = (int*)(ws + off);   off += 4096;
  int*   eb       = (int*)(ws + off);   off += (size_t)E * 4;
  unsigned short* aggb = (unsigned short*)(ws + off); off += (size_t)N * KP1 * 2;
  short* h1       = (short*)(ws + off); off += (size_t)N * KP2 * 2;

  hipMemsetAsync(d_ws, 0, zero_bytes, stream);

  {  // w1: (D x H) fp32 -> wT1: (H rows x KP1 cols) bf16
    int tot = D * H;
    transpose_pad<<<(tot + 255) / 256, 256, 0, stream>>>(w1, wT1, D, H, KP1, tot);
  }
  {  // w2: (H x D) fp32 -> wT2: (D rows x KP2 cols) bf16
    int tot = H * D;
    transpose_pad<<<(tot + 255) / 256, 256, 0, stream>>>(w2, wT2, H, D, KP2, tot);
  }
  // ---- CSR build ----
  count_deg<<<(E + 255) / 256, 256, 0, stream>>>(dst, deg, E);
  scan1<<<nb, 256, 0, stream>>>(deg, offp, bsum, N);
  scan2<<<1, 256, 0, stream>>>(bsum, nb);
  fill_csr<<<(E + 255) / 256, 256, 0, stream>>>(dst, offp, bsum, tmp, eb, E);
  // ---- gather (atomic-free aggregation, bf16 out) ----
  {
    int chunks = KP1 / 16;   // 20
    int total = N * chunks;
    gather_agg<<<(total + 255) / 256, 256, 0, stream>>>(
        nf, src, ef0, ef1, ew0, eb0, ew1, eb1, deg, offp, bsum, eb,
        aggb, D, KP1, chunks, total);
  }
  {  // h1 = relu(aggb @ w1 + b1), bf16 out (stride KP2)
    int grid = (N + 63) / 64;
    gemm_areg<64, KP1, KP1 + 8, KP1 / 32, NP1 / 64, 2, true, false, false>
        <<<grid, 256, 0, stream>>>((const short*)aggb, wT1, b1, h1, KP2, N, H,
                                   nullptr, nullptr);
  }
  {  // h = h1 @ w2 + b2 (+ column stats), fp32 out
    int grid = (N + 31) / 32;
    gemm_areg<32, KP2, KP2 + 8, KP2 / 32, NP2 / 64, 1, false, true, true>
        <<<grid, 256, 0, stream>>>(h1, wT2, b2, d_out, D, N, D, colsum, colsumsq);
  }
  bn_finalize<<<(D + 255) / 256, 256, 0, stream>>>(colsum, colsumsq, gam, bet,
                                                   scale, shiftv, D, 1.0f / (float)N);
  {
    int q4 = D / 4;                 // 75
    int total4 = N * q4;
    bn_apply<<<(total4 + 255) / 256, 256, 0, stream>>>((float*)d_out, scale, shiftv,
                                                       total4, q4);
  }
}